// Round 5
// baseline (228.936 us; speedup 1.0000x reference)
//
#include <hip/hip_runtime.h>

// GraphSAGE layer: out = relu(h @ Ws^T + (scatter_mean(h,src,dst)) @ Wn^T + b)
// N=50000, E=800000, dim 128.
// R5: hist partitioned by dst-range x XCD (R4: 24MB write-amp from cnt atomic
//     line bouncing across non-coherent per-XCD L2s, cast_hist 44us);
//     scan initializes cur=offs (place loses its offs[d] load; memset 200KB);
//     scan 8 nodes/thread (7 iters); cast 16 elems/thread.
constexpr int N_NODES_C = 50000;
constexpr int N_EDGES_C = 800000;
constexpr int DIM_C     = 128;

typedef __attribute__((ext_vector_type(8))) short short8;  // 8 bf16, 4 VGPRs
typedef __attribute__((ext_vector_type(4))) float f32x4;

// Workspace layout (bytes), total ~29.4 MB:
//   [0)        h_bf16  : ushort[N][128]   12.8 MB
//   [OFF_ACC)  acc_bf16: ushort[N][128]   12.8 MB
//   [OFF_CNT)  cnt     : int[N]
//   [OFF_CUR)  cur     : int[N]   (scan writes cur[d]=offs[d]; place bumps)
//   [OFF_OFFS) offs    : int[N+1] (16B-aligned for int4 stores)
//   [OFF_ESRC) esrc    : int[E]
constexpr size_t OFF_ACC  = (size_t)N_NODES_C * DIM_C * 2;          // 12,800,000
constexpr size_t OFF_CNT  = OFF_ACC + (size_t)N_NODES_C * DIM_C * 2;// 25,600,000
constexpr size_t OFF_CUR  = OFF_CNT + (size_t)N_NODES_C * 4;        // 25,800,000
constexpr size_t OFF_OFFS = OFF_CUR + (size_t)N_NODES_C * 4;        // 26,000,000
constexpr size_t OFF_ESRC = OFF_OFFS + ((size_t)N_NODES_C + 4) * 4; // 26,200,016

// round-to-nearest-even f32 -> bf16 bits (finite inputs only)
static __device__ __forceinline__ ushort f2bf(float f) {
  unsigned u = __float_as_uint(f);
  return (ushort)((u + 0x7FFFu + ((u >> 16) & 1u)) >> 16);
}
static __device__ __forceinline__ unsigned pack2(float a, float b) {
  return (unsigned)f2bf(a) | ((unsigned)f2bf(b) << 16);
}

// Edge-chunk geometry shared by hist and place: 196 chunks x 8 partitions.
// part = blockIdx&7 (round-robin block->XCD heuristic; perf only). Block
// (chunk,part) scans its 4096-edge chunk, acts only on dsts in part's
// 6250-node range -> all atomics/writes to a cnt/cur/esrc region come from
// one XCD; lines stay in that L2 and write back once.
constexpr int P_PARTS  = 8;
constexpr int NODES_PP = N_NODES_C / P_PARTS;                         // 6250
constexpr int EPB      = 4096;                                        // edges/chunk
constexpr int NCHUNK   = (N_EDGES_C + EPB - 1) / EPB;                 // 196
constexpr int NB_CAST  = 1563;   // cast blocks: 16 bf16/thread, guarded
constexpr int NB_HIST  = NCHUNK * P_PARTS;                            // 1568

// --------------------------------------------------------------------------
// K0: fused cast(h f32->bf16) + partitioned in-degree histogram.
// --------------------------------------------------------------------------
__global__ __launch_bounds__(256) void sage_cast_hist(
    const float* __restrict__ h, ushort* __restrict__ hb,
    const int* __restrict__ dst, int* __restrict__ cnt)
{
  const int b = blockIdx.x;
  if (b < NB_CAST) {
    int tid = b * 256 + threadIdx.x;
    if (tid < 400000) {                       // 400000*16 = 6.4M elems
      size_t i = (size_t)tid * 16;
      float4 a0 = *reinterpret_cast<const float4*>(h + i);
      float4 a1 = *reinterpret_cast<const float4*>(h + i + 4);
      float4 a2 = *reinterpret_cast<const float4*>(h + i + 8);
      float4 a3 = *reinterpret_cast<const float4*>(h + i + 12);
      uint4 o0, o1;
      o0.x = pack2(a0.x, a0.y); o0.y = pack2(a0.z, a0.w);
      o0.z = pack2(a1.x, a1.y); o0.w = pack2(a1.z, a1.w);
      o1.x = pack2(a2.x, a2.y); o1.y = pack2(a2.z, a2.w);
      o1.z = pack2(a3.x, a3.y); o1.w = pack2(a3.z, a3.w);
      *reinterpret_cast<uint4*>(hb + i)     = o0;
      *reinterpret_cast<uint4*>(hb + i + 8) = o1;
    }
  } else {
    const int part  = b & (P_PARTS - 1);
    const int chunk = (b - NB_CAST) >> 3;
    const int lo = part * NODES_PP;
    const int hi = lo + NODES_PP;
#pragma unroll
    for (int i = 0; i < 4; i++) {
      int e = chunk * EPB + i * 1024 + (int)threadIdx.x * 4;
      if (e < N_EDGES_C) {                    // E%4==0: int4 fully valid
        int4 d4 = *reinterpret_cast<const int4*>(dst + e);
        if (d4.x >= lo && d4.x < hi) atomicAdd(&cnt[d4.x], 1);
        if (d4.y >= lo && d4.y < hi) atomicAdd(&cnt[d4.y], 1);
        if (d4.z >= lo && d4.z < hi) atomicAdd(&cnt[d4.z], 1);
        if (d4.w >= lo && d4.w < hi) atomicAdd(&cnt[d4.w], 1);
      }
    }
  }
}

// --------------------------------------------------------------------------
// K1: exclusive scan cnt[N] -> offs[N+1] AND cur[N] (=offs). Single 1024-thr
// block, 8 nodes/thread via 2x int4 (6250 groups -> 7 iterations).
// --------------------------------------------------------------------------
__global__ __launch_bounds__(1024) void sage_scan(
    const int* __restrict__ cnt, int* __restrict__ offs,
    int* __restrict__ cur)
{
  __shared__ int wsum[16];
  __shared__ int woff[16];
  __shared__ int carry_s;
  const int lane = threadIdx.x & 63;
  const int wid  = threadIdx.x >> 6;
  if (threadIdx.x == 0) carry_s = 0;
  __syncthreads();

  constexpr int NGROUP = N_NODES_C / 8;   // 6250 groups of 8
  for (int base = 0; base < NGROUP; base += 1024) {
    int g = base + threadIdx.x;
    int4 v0 = make_int4(0, 0, 0, 0), v1 = make_int4(0, 0, 0, 0);
    if (g < NGROUP) {
      v0 = *reinterpret_cast<const int4*>(cnt + (size_t)g * 8);
      v1 = *reinterpret_cast<const int4*>(cnt + (size_t)g * 8 + 4);
    }
    int tsum = v0.x + v0.y + v0.z + v0.w + v1.x + v1.y + v1.z + v1.w;
    int x = tsum;
#pragma unroll
    for (int d = 1; d < 64; d <<= 1) {
      int y = __shfl_up(x, d, 64);
      if (lane >= d) x += y;
    }
    if (lane == 63) wsum[wid] = x;
    __syncthreads();
    if (wid == 0) {
      int s = (lane < 16) ? wsum[lane] : 0;
      int xs = s;
#pragma unroll
      for (int d = 1; d < 16; d <<= 1) {
        int y = __shfl_up(xs, d, 64);
        if (lane >= d) xs += y;
      }
      if (lane < 16) woff[lane] = xs - s;
    }
    __syncthreads();
    int c = carry_s;
    if (g < NGROUP) {
      int excl = c + woff[wid] + x - tsum;
      int4 o0, o1;
      o0.x = excl;
      o0.y = o0.x + v0.x; o0.z = o0.y + v0.y; o0.w = o0.z + v0.z;
      o1.x = o0.w + v0.w;
      o1.y = o1.x + v1.x; o1.z = o1.y + v1.y; o1.w = o1.z + v1.z;
      *reinterpret_cast<int4*>(offs + (size_t)g * 8)     = o0;
      *reinterpret_cast<int4*>(offs + (size_t)g * 8 + 4) = o1;
      *reinterpret_cast<int4*>(cur  + (size_t)g * 8)     = o0;
      *reinterpret_cast<int4*>(cur  + (size_t)g * 8 + 4) = o1;
    }
    __syncthreads();                           // all read carry_s first
    if (threadIdx.x == 1023) carry_s = c + woff[15] + x;
    __syncthreads();
  }
  if (threadIdx.x == 0) offs[N_NODES_C] = carry_s;   // == E
}

// --------------------------------------------------------------------------
// K2: place edges into CSR slots, dst-range x XCD partitioned (same chunk
// geometry as hist). cur pre-loaded with offs -> one atomic, no offs read.
// --------------------------------------------------------------------------
__global__ __launch_bounds__(256) void sage_place(
    const int* __restrict__ src, const int* __restrict__ dst,
    int* __restrict__ cur, int* __restrict__ esrc)
{
  const int part  = blockIdx.x & (P_PARTS - 1);
  const int chunk = blockIdx.x >> 3;
  const int lo = part * NODES_PP;
  const int hi = lo + NODES_PP;
#pragma unroll
  for (int i = 0; i < 4; i++) {
    int e = chunk * EPB + i * 1024 + (int)threadIdx.x * 4;
    if (e < N_EDGES_C) {
      int4 d4 = *reinterpret_cast<const int4*>(dst + e);
      if (d4.x >= lo && d4.x < hi) esrc[atomicAdd(&cur[d4.x], 1)] = src[e];
      if (d4.y >= lo && d4.y < hi) esrc[atomicAdd(&cur[d4.y], 1)] = src[e + 1];
      if (d4.z >= lo && d4.z < hi) esrc[atomicAdd(&cur[d4.z], 1)] = src[e + 2];
      if (d4.w >= lo && d4.w < hi) esrc[atomicAdd(&cur[d4.w], 1)] = src[e + 3];
    }
  }
}

// --------------------------------------------------------------------------
// K3: gather-mean in bf16. 32 lanes per dst node, 4 bf16 (8B) per lane.
// f32 accumulate, fold 1/deg, write bf16 acc row once. Unroll-4 for MLP.
// --------------------------------------------------------------------------
__global__ __launch_bounds__(256) void sage_gather(
    const ushort* __restrict__ hb, const int* __restrict__ offs,
    const int* __restrict__ esrc, const float* __restrict__ deg,
    ushort* __restrict__ accb)
{
  int t = blockIdx.x * 256 + threadIdx.x;
  int n = t >> 5;
  int c = (t & 31) << 2;          // 4 bf16 per lane
  int begin = offs[n];
  int end   = offs[n + 1];

  float s0 = 0.f, s1 = 0.f, s2 = 0.f, s3 = 0.f;
  int i = begin;
  for (; i + 3 < end; i += 4) {
    int e0 = esrc[i], e1 = esrc[i + 1], e2 = esrc[i + 2], e3 = esrc[i + 3];
    uint2 a = *reinterpret_cast<const uint2*>(hb + (size_t)e0 * DIM_C + c);
    uint2 b = *reinterpret_cast<const uint2*>(hb + (size_t)e1 * DIM_C + c);
    uint2 d = *reinterpret_cast<const uint2*>(hb + (size_t)e2 * DIM_C + c);
    uint2 f = *reinterpret_cast<const uint2*>(hb + (size_t)e3 * DIM_C + c);
    s0 += __uint_as_float(a.x << 16) + __uint_as_float(b.x << 16)
        + __uint_as_float(d.x << 16) + __uint_as_float(f.x << 16);
    s1 += __uint_as_float(a.x & 0xFFFF0000u) + __uint_as_float(b.x & 0xFFFF0000u)
        + __uint_as_float(d.x & 0xFFFF0000u) + __uint_as_float(f.x & 0xFFFF0000u);
    s2 += __uint_as_float(a.y << 16) + __uint_as_float(b.y << 16)
        + __uint_as_float(d.y << 16) + __uint_as_float(f.y << 16);
    s3 += __uint_as_float(a.y & 0xFFFF0000u) + __uint_as_float(b.y & 0xFFFF0000u)
        + __uint_as_float(d.y & 0xFFFF0000u) + __uint_as_float(f.y & 0xFFFF0000u);
  }
  for (; i < end; i++) {
    int e0 = esrc[i];
    uint2 a = *reinterpret_cast<const uint2*>(hb + (size_t)e0 * DIM_C + c);
    s0 += __uint_as_float(a.x << 16);
    s1 += __uint_as_float(a.x & 0xFFFF0000u);
    s2 += __uint_as_float(a.y << 16);
    s3 += __uint_as_float(a.y & 0xFFFF0000u);
  }
  float id = 1.0f / deg[n];
  uint2 o;
  o.x = pack2(s0 * id, s1 * id);
  o.y = pack2(s2 * id, s3 * id);
  *reinterpret_cast<uint2*>(accb + (size_t)n * DIM_C + c) = o;
}

// --------------------------------------------------------------------------
// K4: fused bf16 MFMA GEMM, K=256 (k<128 from h_bf16, k>=128 from acc_bf16).
// Block = 256 thr (4 waves), 64 rows/block. W staged bf16 in LDS (67.6 KB).
// Layouts (m89/m91-verified): A[m=lane&15][k=quad*8+j];
// B from W[n][k] with n=lane&15, k=quad*8+j; C/D col=lane&15, row=quad*4+reg.
// --------------------------------------------------------------------------
__global__ __launch_bounds__(256) void sage_gemm_mfma(
    const ushort* __restrict__ hb, const ushort* __restrict__ accb,
    const float* __restrict__ Wself, const float* __restrict__ Wneigh,
    const float* __restrict__ bias, float* __restrict__ out)
{
  __shared__ ushort Bl[DIM_C][256 + 8];   // 67,584 B
  __shared__ float  bias_l[DIM_C];

  const int t = threadIdx.x;

  for (int idx = t; idx < DIM_C * 32; idx += 256) {
    int n  = idx >> 5;
    int k4 = (idx & 31) << 2;
    float4 ws4 = *reinterpret_cast<const float4*>(Wself  + n * DIM_C + k4);
    float4 wn4 = *reinterpret_cast<const float4*>(Wneigh + n * DIM_C + k4);
    *reinterpret_cast<uint2*>(&Bl[n][k4]) =
        make_uint2(pack2(ws4.x, ws4.y), pack2(ws4.z, ws4.w));
    *reinterpret_cast<uint2*>(&Bl[n][128 + k4]) =
        make_uint2(pack2(wn4.x, wn4.y), pack2(wn4.z, wn4.w));
  }
  if (t < DIM_C) bias_l[t] = bias[t];
  __syncthreads();

  const int lane = t & 63;
  const int w    = t >> 6;
  const int am   = lane & 15;
  const int q    = lane >> 4;
  const int m0   = blockIdx.x * 64 + w * 16;

  int r = m0 + am;
  if (r >= N_NODES_C) r = N_NODES_C - 1;   // clamp; stores guarded below
  const ushort* aph = hb   + (size_t)r * DIM_C + q * 8;
  const ushort* apa = accb + (size_t)r * DIM_C + q * 8;

  f32x4 acc[8];
#pragma unroll
  for (int nt = 0; nt < 8; nt++) acc[nt] = (f32x4){0.f, 0.f, 0.f, 0.f};

#pragma unroll
  for (int ks = 0; ks < 4; ks++) {
    short8 af = *reinterpret_cast<const short8*>(aph + ks * 32);
#pragma unroll
    for (int nt = 0; nt < 8; nt++) {
      short8 bf = *reinterpret_cast<const short8*>(&Bl[nt * 16 + am][ks * 32 + q * 8]);
      acc[nt] = __builtin_amdgcn_mfma_f32_16x16x32_bf16(af, bf, acc[nt], 0, 0, 0);
    }
  }
#pragma unroll
  for (int ks = 0; ks < 4; ks++) {
    short8 af = *reinterpret_cast<const short8*>(apa + ks * 32);
#pragma unroll
    for (int nt = 0; nt < 8; nt++) {
      short8 bf = *reinterpret_cast<const short8*>(&Bl[nt * 16 + am][128 + ks * 32 + q * 8]);
      acc[nt] = __builtin_amdgcn_mfma_f32_16x16x32_bf16(af, bf, acc[nt], 0, 0, 0);
    }
  }

#pragma unroll
  for (int nt = 0; nt < 8; nt++) {
    int col = nt * 16 + am;
    float bv = bias_l[col];
#pragma unroll
    for (int rr = 0; rr < 4; rr++) {
      int row = m0 + q * 4 + rr;
      if (row < N_NODES_C) {
        float v = acc[nt][rr] + bv;
        out[(size_t)row * DIM_C + col] = fmaxf(v, 0.f);
      }
    }
  }
}

// --------------------------------------------------------------------------
extern "C" void kernel_launch(void* const* d_in, const int* in_sizes, int n_in,
                              void* d_out, int out_size, void* d_ws, size_t ws_size,
                              hipStream_t stream) {
  const float* h      = (const float*)d_in[0];
  const int*   src    = (const int*)d_in[1];
  const int*   dst    = (const int*)d_in[2];
  const float* deg    = (const float*)d_in[3];
  const float* Wself  = (const float*)d_in[4];
  const float* Wneigh = (const float*)d_in[5];
  const float* bias   = (const float*)d_in[6];
  float*       out    = (float*)d_out;

  char* ws = (char*)d_ws;
  ushort* hb   = (ushort*)ws;
  ushort* accb = (ushort*)(ws + OFF_ACC);
  int*    cnt  = (int*)(ws + OFF_CNT);
  int*    cur  = (int*)(ws + OFF_CUR);
  int*    offs = (int*)(ws + OFF_OFFS);
  int*    esrc = (int*)(ws + OFF_ESRC);

  // Zero cnt only (200KB); cur/offs/esrc/acc fully overwritten downstream.
  hipMemsetAsync(cnt, 0, (size_t)N_NODES_C * sizeof(int), stream);

  sage_cast_hist<<<NB_CAST + NB_HIST, 256, 0, stream>>>(h, hb, dst, cnt);
  sage_scan     <<<1, 1024, 0, stream>>>(cnt, offs, cur);
  sage_place    <<<NB_HIST, 256, 0, stream>>>(src, dst, cur, esrc);
  sage_gather   <<<(N_NODES_C * 32) / 256, 256, 0, stream>>>(hb, offs, esrc, deg, accb);
  sage_gemm_mfma<<<(N_NODES_C + 63) / 64, 256, 0, stream>>>(hb, accb, Wself,
                                                            Wneigh, bias, out);
}

// Round 6
// 154.489 us; speedup vs baseline: 1.4819x; 1.4819x over previous
//
#include <hip/hip_runtime.h>

// GraphSAGE layer: out = relu(h @ Ws^T + (scatter_mean(h,src,dst)) @ Wn^T + b)
// N=50000, E=800000, dim 128.
// R6: kill the two 800k-global-atomic passes (hist 44us + place ~44us; R5
//     proved the cost is per-atomic at the memory-side coherence point,
//     ~18 atomics/ns, insensitive to XCD partitioning). Replace with MSD
//     bucket sort (bucket = dst>>8): LDS-atomic histograms + 38k bulk
//     reservation atomics + per-bucket LDS counting sort. Edge packs into
//     one uint32 since N < 2^16.
constexpr int N_NODES_C = 50000;
constexpr int N_EDGES_C = 800000;
constexpr int DIM_C     = 128;

constexpr int NBKT  = 196;    // (50000+255)>>8
constexpr int CAP   = 8192;   // bucket capacity; mean fill 4096, sd ~64
constexpr int NB_CASTK = 391; // cast blocks: 1024 thr x 16 elems, guarded
constexpr int NB_SCAT  = 196; // scatter blocks: 4096 edges each

typedef __attribute__((ext_vector_type(8))) short short8;  // 8 bf16, 4 VGPRs
typedef __attribute__((ext_vector_type(4))) float f32x4;

// Workspace layout (bytes), total ~38.8 MB (ws is 256MB+ per harness fill):
constexpr size_t OFF_HB   = 0;                                   // ushort[N][128]
constexpr size_t OFF_ACC  = (size_t)N_NODES_C * DIM_C * 2;       // 12,800,000
constexpr size_t OFF_PK   = OFF_ACC + (size_t)N_NODES_C * DIM_C * 2;  // 25,600,000
constexpr size_t OFF_ESRC = OFF_PK + (size_t)NBKT * CAP * 4;     // 32,022,528
constexpr size_t OFF_ST   = OFF_ESRC + (size_t)NBKT * CAP * 4;   // 38,445,056
constexpr size_t OFF_EN   = OFF_ST + (size_t)N_NODES_C * 4;      // 38,645,056
constexpr size_t OFF_GC   = OFF_EN + (size_t)N_NODES_C * 4;      // 38,845,056

// round-to-nearest-even f32 -> bf16 bits (finite inputs only)
static __device__ __forceinline__ ushort f2bf(float f) {
  unsigned u = __float_as_uint(f);
  return (ushort)((u + 0x7FFFu + ((u >> 16) & 1u)) >> 16);
}
static __device__ __forceinline__ unsigned pack2(float a, float b) {
  return (unsigned)f2bf(a) | ((unsigned)f2bf(b) << 16);
}

// --------------------------------------------------------------------------
// K_A: fused cast(h f32->bf16) + bucket scatter of packed edges.
// Blocks [0,NB_CASTK): cast 16 elems/thread.
// Blocks [NB_CASTK, NB_CASTK+NB_SCAT): 4096 edges -> LDS hist over 196
//   buckets -> one global atomicAdd per nonzero bin (bulk reserve) ->
//   scatter ((dst&255)<<16)|src into bucket runs. Per-edge atomics: LDS only.
// --------------------------------------------------------------------------
__global__ __launch_bounds__(1024) void sage_cast_bucket(
    const float* __restrict__ h, ushort* __restrict__ hb,
    const int* __restrict__ src, const int* __restrict__ dst,
    int* __restrict__ gcur, unsigned* __restrict__ packed)
{
  const int b = blockIdx.x;
  const int t = threadIdx.x;
  if (b < NB_CASTK) {
    int tid = b * 1024 + t;
    if (tid < 400000) {                       // 400000*16 = 6.4M elems
      size_t i = (size_t)tid * 16;
      float4 a0 = *reinterpret_cast<const float4*>(h + i);
      float4 a1 = *reinterpret_cast<const float4*>(h + i + 4);
      float4 a2 = *reinterpret_cast<const float4*>(h + i + 8);
      float4 a3 = *reinterpret_cast<const float4*>(h + i + 12);
      uint4 o0, o1;
      o0.x = pack2(a0.x, a0.y); o0.y = pack2(a0.z, a0.w);
      o0.z = pack2(a1.x, a1.y); o0.w = pack2(a1.z, a1.w);
      o1.x = pack2(a2.x, a2.y); o1.y = pack2(a2.z, a2.w);
      o1.z = pack2(a3.x, a3.y); o1.w = pack2(a3.z, a3.w);
      *reinterpret_cast<uint4*>(hb + i)     = o0;
      *reinterpret_cast<uint4*>(hb + i + 8) = o1;
    }
    return;
  }

  __shared__ int bh[NBKT];     // per-bucket count
  __shared__ int bofs[NBKT];   // reserved base in bucket region
  __shared__ int bcur[NBKT];   // local cursor

  const int chunk = b - NB_CASTK;
  const int e = chunk * 4096 + t * 4;        // E%4==0: int4 valid when e<E

  if (t < NBKT) bh[t] = 0;
  __syncthreads();

  int4 d4, s4;
  bool live = (e < N_EDGES_C);
  if (live) {
    d4 = *reinterpret_cast<const int4*>(dst + e);
    s4 = *reinterpret_cast<const int4*>(src + e);
    atomicAdd(&bh[d4.x >> 8], 1);
    atomicAdd(&bh[d4.y >> 8], 1);
    atomicAdd(&bh[d4.z >> 8], 1);
    atomicAdd(&bh[d4.w >> 8], 1);
  }
  __syncthreads();

  if (t < NBKT) {
    bcur[t] = 0;
    bofs[t] = (bh[t] > 0) ? atomicAdd(&gcur[t], bh[t]) : 0;
  }
  __syncthreads();

  if (live) {
    int dd[4] = {d4.x, d4.y, d4.z, d4.w};
    int ss[4] = {s4.x, s4.y, s4.z, s4.w};
#pragma unroll
    for (int i = 0; i < 4; i++) {
      int bkt = dd[i] >> 8;
      int p = bofs[bkt] + atomicAdd(&bcur[bkt], 1);
      if (p < CAP)   // statistically unreachable; memory-safety guard
        packed[(size_t)bkt * CAP + p] =
            ((unsigned)(dd[i] & 255) << 16) | (unsigned)ss[i];
    }
  }
}

// --------------------------------------------------------------------------
// K_B: per-bucket LDS counting sort -> CSR (starts/ends absolute into esrc)
// + esrc placement. One 1024-thr block per bucket; all edges of nodes
// [b*256,(b+1)*256) are in bucket b, so no cross-bucket scan is needed.
// --------------------------------------------------------------------------
__global__ __launch_bounds__(1024) void sage_csr(
    const unsigned* __restrict__ packed, const int* __restrict__ gcur,
    int* __restrict__ starts, int* __restrict__ ends,
    int* __restrict__ esrc)
{
  __shared__ int hist[256];
  __shared__ int excl[256];
  __shared__ int curb[256];

  const int b = blockIdx.x;
  const int t = threadIdx.x;
  const int count = min(gcur[b], CAP);
  const unsigned* pk = packed + (size_t)b * CAP;

  if (t < 256) hist[t] = 0;
  __syncthreads();

  for (int i = t; i < count; i += 1024)
    atomicAdd(&hist[pk[i] >> 16], 1);
  __syncthreads();

  // exclusive scan of hist[256] by wave 0: lane l owns bins 4l..4l+3
  if (t < 64) {
    int base = t * 4;
    int h0 = hist[base], h1 = hist[base + 1], h2 = hist[base + 2], h3 = hist[base + 3];
    int s = h0 + h1 + h2 + h3;
    int x = s;
#pragma unroll
    for (int d = 1; d < 64; d <<= 1) {
      int y = __shfl_up(x, d, 64);
      if (t >= d) x += y;
    }
    int ex = x - s;
    excl[base]     = ex;
    excl[base + 1] = ex + h0;
    excl[base + 2] = ex + h0 + h1;
    excl[base + 3] = ex + h0 + h1 + h2;
  }
  __syncthreads();

  if (t < 256) {
    int n = (b << 8) | t;
    if (n < N_NODES_C) {
      int s = b * CAP + excl[t];
      starts[n] = s;
      ends[n]   = s + hist[t];
    }
    curb[t] = excl[t];
  }
  __syncthreads();

  for (int i = t; i < count; i += 1024) {
    unsigned w = pk[i];
    int r = w >> 16;
    int p = atomicAdd(&curb[r], 1);
    esrc[b * CAP + p] = (int)(w & 0xFFFFu);
  }
}

// --------------------------------------------------------------------------
// K3: gather-mean in bf16. 32 lanes per dst node, 4 bf16 (8B) per lane.
// f32 accumulate, fold 1/deg, write bf16 acc row once. Unroll-4 for MLP.
// --------------------------------------------------------------------------
__global__ __launch_bounds__(256) void sage_gather(
    const ushort* __restrict__ hb, const int* __restrict__ starts,
    const int* __restrict__ ends, const int* __restrict__ esrc,
    const float* __restrict__ deg, ushort* __restrict__ accb)
{
  int t = blockIdx.x * 256 + threadIdx.x;
  int n = t >> 5;
  int c = (t & 31) << 2;          // 4 bf16 per lane
  int begin = starts[n];
  int end   = ends[n];

  float s0 = 0.f, s1 = 0.f, s2 = 0.f, s3 = 0.f;
  int i = begin;
  for (; i + 3 < end; i += 4) {
    int e0 = esrc[i], e1 = esrc[i + 1], e2 = esrc[i + 2], e3 = esrc[i + 3];
    uint2 a = *reinterpret_cast<const uint2*>(hb + (size_t)e0 * DIM_C + c);
    uint2 b = *reinterpret_cast<const uint2*>(hb + (size_t)e1 * DIM_C + c);
    uint2 d = *reinterpret_cast<const uint2*>(hb + (size_t)e2 * DIM_C + c);
    uint2 f = *reinterpret_cast<const uint2*>(hb + (size_t)e3 * DIM_C + c);
    s0 += __uint_as_float(a.x << 16) + __uint_as_float(b.x << 16)
        + __uint_as_float(d.x << 16) + __uint_as_float(f.x << 16);
    s1 += __uint_as_float(a.x & 0xFFFF0000u) + __uint_as_float(b.x & 0xFFFF0000u)
        + __uint_as_float(d.x & 0xFFFF0000u) + __uint_as_float(f.x & 0xFFFF0000u);
    s2 += __uint_as_float(a.y << 16) + __uint_as_float(b.y << 16)
        + __uint_as_float(d.y << 16) + __uint_as_float(f.y << 16);
    s3 += __uint_as_float(a.y & 0xFFFF0000u) + __uint_as_float(b.y & 0xFFFF0000u)
        + __uint_as_float(d.y & 0xFFFF0000u) + __uint_as_float(f.y & 0xFFFF0000u);
  }
  for (; i < end; i++) {
    int e0 = esrc[i];
    uint2 a = *reinterpret_cast<const uint2*>(hb + (size_t)e0 * DIM_C + c);
    s0 += __uint_as_float(a.x << 16);
    s1 += __uint_as_float(a.x & 0xFFFF0000u);
    s2 += __uint_as_float(a.y << 16);
    s3 += __uint_as_float(a.y & 0xFFFF0000u);
  }
  float id = 1.0f / deg[n];
  uint2 o;
  o.x = pack2(s0 * id, s1 * id);
  o.y = pack2(s2 * id, s3 * id);
  *reinterpret_cast<uint2*>(accb + (size_t)n * DIM_C + c) = o;
}

// --------------------------------------------------------------------------
// K4: fused bf16 MFMA GEMM, K=256 (k<128 from h_bf16, k>=128 from acc_bf16).
// Block = 256 thr (4 waves), 64 rows/block. W staged bf16 in LDS (67.6 KB).
// Layouts (m89/m91-verified): A[m=lane&15][k=quad*8+j];
// B from W[n][k] with n=lane&15, k=quad*8+j; C/D col=lane&15, row=quad*4+reg.
// --------------------------------------------------------------------------
__global__ __launch_bounds__(256) void sage_gemm_mfma(
    const ushort* __restrict__ hb, const ushort* __restrict__ accb,
    const float* __restrict__ Wself, const float* __restrict__ Wneigh,
    const float* __restrict__ bias, float* __restrict__ out)
{
  __shared__ ushort Bl[DIM_C][256 + 8];   // 67,584 B
  __shared__ float  bias_l[DIM_C];

  const int t = threadIdx.x;

  for (int idx = t; idx < DIM_C * 32; idx += 256) {
    int n  = idx >> 5;
    int k4 = (idx & 31) << 2;
    float4 ws4 = *reinterpret_cast<const float4*>(Wself  + n * DIM_C + k4);
    float4 wn4 = *reinterpret_cast<const float4*>(Wneigh + n * DIM_C + k4);
    *reinterpret_cast<uint2*>(&Bl[n][k4]) =
        make_uint2(pack2(ws4.x, ws4.y), pack2(ws4.z, ws4.w));
    *reinterpret_cast<uint2*>(&Bl[n][128 + k4]) =
        make_uint2(pack2(wn4.x, wn4.y), pack2(wn4.z, wn4.w));
  }
  if (t < DIM_C) bias_l[t] = bias[t];
  __syncthreads();

  const int lane = t & 63;
  const int w    = t >> 6;
  const int am   = lane & 15;
  const int q    = lane >> 4;
  const int m0   = blockIdx.x * 64 + w * 16;

  int r = m0 + am;
  if (r >= N_NODES_C) r = N_NODES_C - 1;   // clamp; stores guarded below
  const ushort* aph = hb   + (size_t)r * DIM_C + q * 8;
  const ushort* apa = accb + (size_t)r * DIM_C + q * 8;

  f32x4 acc[8];
#pragma unroll
  for (int nt = 0; nt < 8; nt++) acc[nt] = (f32x4){0.f, 0.f, 0.f, 0.f};

#pragma unroll
  for (int ks = 0; ks < 4; ks++) {
    short8 af = *reinterpret_cast<const short8*>(aph + ks * 32);
#pragma unroll
    for (int nt = 0; nt < 8; nt++) {
      short8 bf = *reinterpret_cast<const short8*>(&Bl[nt * 16 + am][ks * 32 + q * 8]);
      acc[nt] = __builtin_amdgcn_mfma_f32_16x16x32_bf16(af, bf, acc[nt], 0, 0, 0);
    }
  }
#pragma unroll
  for (int ks = 0; ks < 4; ks++) {
    short8 af = *reinterpret_cast<const short8*>(apa + ks * 32);
#pragma unroll
    for (int nt = 0; nt < 8; nt++) {
      short8 bf = *reinterpret_cast<const short8*>(&Bl[nt * 16 + am][128 + ks * 32 + q * 8]);
      acc[nt] = __builtin_amdgcn_mfma_f32_16x16x32_bf16(af, bf, acc[nt], 0, 0, 0);
    }
  }

#pragma unroll
  for (int nt = 0; nt < 8; nt++) {
    int col = nt * 16 + am;
    float bv = bias_l[col];
#pragma unroll
    for (int rr = 0; rr < 4; rr++) {
      int row = m0 + q * 4 + rr;
      if (row < N_NODES_C) {
        float v = acc[nt][rr] + bv;
        out[(size_t)row * DIM_C + col] = fmaxf(v, 0.f);
      }
    }
  }
}

// --------------------------------------------------------------------------
extern "C" void kernel_launch(void* const* d_in, const int* in_sizes, int n_in,
                              void* d_out, int out_size, void* d_ws, size_t ws_size,
                              hipStream_t stream) {
  const float* h      = (const float*)d_in[0];
  const int*   src    = (const int*)d_in[1];
  const int*   dst    = (const int*)d_in[2];
  const float* deg    = (const float*)d_in[3];
  const float* Wself  = (const float*)d_in[4];
  const float* Wneigh = (const float*)d_in[5];
  const float* bias   = (const float*)d_in[6];
  float*       out    = (float*)d_out;

  char* ws = (char*)d_ws;
  ushort*   hb     = (ushort*)(ws + OFF_HB);
  ushort*   accb   = (ushort*)(ws + OFF_ACC);
  unsigned* packed = (unsigned*)(ws + OFF_PK);
  int*      esrc   = (int*)(ws + OFF_ESRC);
  int*      starts = (int*)(ws + OFF_ST);
  int*      ends   = (int*)(ws + OFF_EN);
  int*      gcur   = (int*)(ws + OFF_GC);

  // Zero the 196 bucket cursors only (784 B); all else fully overwritten.
  hipMemsetAsync(gcur, 0, NBKT * sizeof(int), stream);

  sage_cast_bucket<<<NB_CASTK + NB_SCAT, 1024, 0, stream>>>(h, hb, src, dst,
                                                            gcur, packed);
  sage_csr        <<<NBKT, 1024, 0, stream>>>(packed, gcur, starts, ends, esrc);
  sage_gather     <<<(N_NODES_C * 32) / 256, 256, 0, stream>>>(hb, starts, ends,
                                                               esrc, deg, accb);
  sage_gemm_mfma  <<<(N_NODES_C + 63) / 64, 256, 0, stream>>>(hb, accb, Wself,
                                                              Wneigh, bias, out);
}

// Round 7
// 144.215 us; speedup vs baseline: 1.5875x; 1.0712x over previous
//
#include <hip/hip_runtime.h>

// GraphSAGE layer: out = relu(h @ Ws^T + (scatter_mean(h,src,dst)) @ Wn^T + b)
// N=50000, E=800000, dim 128.
// R7: (a) gather 16 lanes/node x uint4 (halves VMEM instr count; it is
//     issue/latency-bound, traffic is L3-served); (b) W pre-cast to bf16 once
//     -> gemm staging halves bytes and loses its 128 pack2/thread prologue
//     (global_load_lds rejected: needs unpadded LDS -> 16-way conflicts).
constexpr int N_NODES_C = 50000;
constexpr int N_EDGES_C = 800000;
constexpr int DIM_C     = 128;

constexpr int NBKT  = 196;    // (50000+255)>>8
constexpr int CAP   = 8192;   // bucket capacity; mean fill 4096, sd ~64
constexpr int NB_CASTK = 391; // h-cast blocks: 1024 thr x 16 elems, guarded
constexpr int NB_WCAST = 2;   // W-cast blocks: one per matrix
constexpr int NB_SCAT  = 196; // bucket-scatter blocks: 4096 edges each

typedef __attribute__((ext_vector_type(8))) short short8;  // 8 bf16, 4 VGPRs
typedef __attribute__((ext_vector_type(4))) float f32x4;

// Workspace layout (bytes), ~38.9 MB total:
constexpr size_t OFF_HB   = 0;                                   // ushort[N][128]
constexpr size_t OFF_ACC  = (size_t)N_NODES_C * DIM_C * 2;       // 12,800,000
constexpr size_t OFF_PK   = OFF_ACC + (size_t)N_NODES_C * DIM_C * 2;  // 25,600,000
constexpr size_t OFF_ESRC = OFF_PK + (size_t)NBKT * CAP * 4;     // 32,022,528
constexpr size_t OFF_ST   = OFF_ESRC + (size_t)NBKT * CAP * 4;   // 38,445,056
constexpr size_t OFF_EN   = OFF_ST + (size_t)N_NODES_C * 4;      // 38,645,056
constexpr size_t OFF_GC   = OFF_EN + (size_t)N_NODES_C * 4;      // 38,845,056
constexpr size_t OFF_WB   = OFF_GC + 1024;                       // ushort[2][128][128]

// round-to-nearest-even f32 -> bf16 bits (finite inputs only)
static __device__ __forceinline__ ushort f2bf(float f) {
  unsigned u = __float_as_uint(f);
  return (ushort)((u + 0x7FFFu + ((u >> 16) & 1u)) >> 16);
}
static __device__ __forceinline__ unsigned pack2(float a, float b) {
  return (unsigned)f2bf(a) | ((unsigned)f2bf(b) << 16);
}

// --------------------------------------------------------------------------
// K_A: fused cast(h) + cast(W) + bucket scatter of packed edges.
// [0,NB_CASTK): h f32->bf16, 16 elems/thread.
// [NB_CASTK, +NB_WCAST): Wself/Wneigh f32->bf16 (16384 elems each).
// rest: 4096 edges -> LDS hist over 196 buckets -> one global atomicAdd per
//   nonzero bin (bulk reserve, ~38k total) -> scatter ((dst&255)<<16)|src.
// --------------------------------------------------------------------------
__global__ __launch_bounds__(1024) void sage_cast_bucket(
    const float* __restrict__ h, ushort* __restrict__ hb,
    const float* __restrict__ Wself, const float* __restrict__ Wneigh,
    ushort* __restrict__ wb,
    const int* __restrict__ src, const int* __restrict__ dst,
    int* __restrict__ gcur, unsigned* __restrict__ packed)
{
  const int b = blockIdx.x;
  const int t = threadIdx.x;
  if (b < NB_CASTK + NB_WCAST) {
    const float* sp;
    ushort* dp;
    size_t i;
    if (b < NB_CASTK) {
      int tid = b * 1024 + t;
      if (tid >= 400000) return;              // 400000*16 = 6.4M elems
      sp = h; dp = hb; i = (size_t)tid * 16;
    } else {
      int m = b - NB_CASTK;                   // 0: Wself, 1: Wneigh
      sp = m ? Wneigh : Wself;
      dp = wb + (size_t)m * DIM_C * DIM_C;
      i = (size_t)t * 16;                     // 1024*16 = 16384 exactly
    }
    float4 a0 = *reinterpret_cast<const float4*>(sp + i);
    float4 a1 = *reinterpret_cast<const float4*>(sp + i + 4);
    float4 a2 = *reinterpret_cast<const float4*>(sp + i + 8);
    float4 a3 = *reinterpret_cast<const float4*>(sp + i + 12);
    uint4 o0, o1;
    o0.x = pack2(a0.x, a0.y); o0.y = pack2(a0.z, a0.w);
    o0.z = pack2(a1.x, a1.y); o0.w = pack2(a1.z, a1.w);
    o1.x = pack2(a2.x, a2.y); o1.y = pack2(a2.z, a2.w);
    o1.z = pack2(a3.x, a3.y); o1.w = pack2(a3.z, a3.w);
    *reinterpret_cast<uint4*>(dp + i)     = o0;
    *reinterpret_cast<uint4*>(dp + i + 8) = o1;
    return;
  }

  __shared__ int bh[NBKT];     // per-bucket count
  __shared__ int bofs[NBKT];   // reserved base in bucket region
  __shared__ int bcur[NBKT];   // local cursor

  const int chunk = b - NB_CASTK - NB_WCAST;
  const int e = chunk * 4096 + t * 4;        // E%4==0: int4 valid when e<E

  if (t < NBKT) bh[t] = 0;
  __syncthreads();

  int4 d4, s4;
  bool live = (e < N_EDGES_C);
  if (live) {
    d4 = *reinterpret_cast<const int4*>(dst + e);
    s4 = *reinterpret_cast<const int4*>(src + e);
    atomicAdd(&bh[d4.x >> 8], 1);
    atomicAdd(&bh[d4.y >> 8], 1);
    atomicAdd(&bh[d4.z >> 8], 1);
    atomicAdd(&bh[d4.w >> 8], 1);
  }
  __syncthreads();

  if (t < NBKT) {
    bcur[t] = 0;
    bofs[t] = (bh[t] > 0) ? atomicAdd(&gcur[t], bh[t]) : 0;
  }
  __syncthreads();

  if (live) {
    int dd[4] = {d4.x, d4.y, d4.z, d4.w};
    int ss[4] = {s4.x, s4.y, s4.z, s4.w};
#pragma unroll
    for (int i = 0; i < 4; i++) {
      int bkt = dd[i] >> 8;
      int p = bofs[bkt] + atomicAdd(&bcur[bkt], 1);
      if (p < CAP)   // statistically unreachable; memory-safety guard
        packed[(size_t)bkt * CAP + p] =
            ((unsigned)(dd[i] & 255) << 16) | (unsigned)ss[i];
    }
  }
}

// --------------------------------------------------------------------------
// K_B: per-bucket LDS counting sort -> CSR (starts/ends absolute into esrc)
// + esrc placement. One 1024-thr block per bucket.
// --------------------------------------------------------------------------
__global__ __launch_bounds__(1024) void sage_csr(
    const unsigned* __restrict__ packed, const int* __restrict__ gcur,
    int* __restrict__ starts, int* __restrict__ ends,
    int* __restrict__ esrc)
{
  __shared__ int hist[256];
  __shared__ int excl[256];
  __shared__ int curb[256];

  const int b = blockIdx.x;
  const int t = threadIdx.x;
  const int count = min(gcur[b], CAP);
  const unsigned* pk = packed + (size_t)b * CAP;

  if (t < 256) hist[t] = 0;
  __syncthreads();

  for (int i = t; i < count; i += 1024)
    atomicAdd(&hist[pk[i] >> 16], 1);
  __syncthreads();

  // exclusive scan of hist[256] by wave 0: lane l owns bins 4l..4l+3
  if (t < 64) {
    int base = t * 4;
    int h0 = hist[base], h1 = hist[base + 1], h2 = hist[base + 2], h3 = hist[base + 3];
    int s = h0 + h1 + h2 + h3;
    int x = s;
#pragma unroll
    for (int d = 1; d < 64; d <<= 1) {
      int y = __shfl_up(x, d, 64);
      if (t >= d) x += y;
    }
    int ex = x - s;
    excl[base]     = ex;
    excl[base + 1] = ex + h0;
    excl[base + 2] = ex + h0 + h1;
    excl[base + 3] = ex + h0 + h1 + h2;
  }
  __syncthreads();

  if (t < 256) {
    int n = (b << 8) | t;
    if (n < N_NODES_C) {
      int s = b * CAP + excl[t];
      starts[n] = s;
      ends[n]   = s + hist[t];
    }
    curb[t] = excl[t];
  }
  __syncthreads();

  for (int i = t; i < count; i += 1024) {
    unsigned w = pk[i];
    int r = w >> 16;
    int p = atomicAdd(&curb[r], 1);
    esrc[b * CAP + p] = (int)(w & 0xFFFFu);
  }
}

// --------------------------------------------------------------------------
// K3: gather-mean in bf16. 16 lanes per dst node, 8 bf16 (uint4, 16B) per
// lane. f32 accumulate (8 sums), fold 1/deg, write bf16 row once. Unroll-4.
// --------------------------------------------------------------------------
__global__ __launch_bounds__(256) void sage_gather(
    const ushort* __restrict__ hb, const int* __restrict__ starts,
    const int* __restrict__ ends, const int* __restrict__ esrc,
    const float* __restrict__ deg, ushort* __restrict__ accb)
{
  int t = blockIdx.x * 256 + threadIdx.x;
  int n = t >> 4;
  int c = (t & 15) << 3;          // 8 bf16 per lane
  int begin = starts[n];
  int end   = ends[n];

  float s0 = 0.f, s1 = 0.f, s2 = 0.f, s3 = 0.f;
  float s4 = 0.f, s5 = 0.f, s6 = 0.f, s7 = 0.f;

#define ACC8(u)                                                  \
  do {                                                           \
    s0 += __uint_as_float((u).x << 16);                          \
    s1 += __uint_as_float((u).x & 0xFFFF0000u);                  \
    s2 += __uint_as_float((u).y << 16);                          \
    s3 += __uint_as_float((u).y & 0xFFFF0000u);                  \
    s4 += __uint_as_float((u).z << 16);                          \
    s5 += __uint_as_float((u).z & 0xFFFF0000u);                  \
    s6 += __uint_as_float((u).w << 16);                          \
    s7 += __uint_as_float((u).w & 0xFFFF0000u);                  \
  } while (0)

  int i = begin;
  for (; i + 3 < end; i += 4) {
    int e0 = esrc[i], e1 = esrc[i + 1], e2 = esrc[i + 2], e3 = esrc[i + 3];
    uint4 a = *reinterpret_cast<const uint4*>(hb + (size_t)e0 * DIM_C + c);
    uint4 b = *reinterpret_cast<const uint4*>(hb + (size_t)e1 * DIM_C + c);
    uint4 d = *reinterpret_cast<const uint4*>(hb + (size_t)e2 * DIM_C + c);
    uint4 f = *reinterpret_cast<const uint4*>(hb + (size_t)e3 * DIM_C + c);
    ACC8(a); ACC8(b); ACC8(d); ACC8(f);
  }
  for (; i < end; i++) {
    int e0 = esrc[i];
    uint4 a = *reinterpret_cast<const uint4*>(hb + (size_t)e0 * DIM_C + c);
    ACC8(a);
  }
#undef ACC8

  float id = 1.0f / deg[n];
  uint4 o;
  o.x = pack2(s0 * id, s1 * id);
  o.y = pack2(s2 * id, s3 * id);
  o.z = pack2(s4 * id, s5 * id);
  o.w = pack2(s6 * id, s7 * id);
  *reinterpret_cast<uint4*>(accb + (size_t)n * DIM_C + c) = o;
}

// --------------------------------------------------------------------------
// K4: fused bf16 MFMA GEMM, K=256 (k<128 from h_bf16, k>=128 from acc_bf16).
// Block = 256 thr (4 waves), 64 rows/block. W staged from pre-cast bf16
// global into padded LDS (uint4 copies, no pack VALU).
// Layouts (m89/m91-verified): A[m=lane&15][k=quad*8+j];
// B from W[n][k] with n=lane&15, k=quad*8+j; C/D col=lane&15, row=quad*4+reg.
// --------------------------------------------------------------------------
__global__ __launch_bounds__(256) void sage_gemm_mfma(
    const ushort* __restrict__ hb, const ushort* __restrict__ accb,
    const ushort* __restrict__ wb, const float* __restrict__ bias,
    float* __restrict__ out)
{
  __shared__ ushort Bl[DIM_C][256 + 8];   // 67,584 B
  __shared__ float  bias_l[DIM_C];

  const int t = threadIdx.x;

  // Stage both W matrices: 128 rows x 16 uint4-chunks each, uint4 copies.
  for (int idx = t; idx < DIM_C * 16; idx += 256) {
    int n  = idx >> 4;
    int c8 = (idx & 15) << 3;
    uint4 w0 = *reinterpret_cast<const uint4*>(wb + (size_t)n * DIM_C + c8);
    uint4 w1 = *reinterpret_cast<const uint4*>(wb + (size_t)(DIM_C + n) * DIM_C + c8);
    *reinterpret_cast<uint4*>(&Bl[n][c8])       = w0;
    *reinterpret_cast<uint4*>(&Bl[n][128 + c8]) = w1;
  }
  if (t < DIM_C) bias_l[t] = bias[t];
  __syncthreads();

  const int lane = t & 63;
  const int w    = t >> 6;
  const int am   = lane & 15;
  const int q    = lane >> 4;
  const int m0   = blockIdx.x * 64 + w * 16;

  int r = m0 + am;
  if (r >= N_NODES_C) r = N_NODES_C - 1;   // clamp; stores guarded below
  const ushort* aph = hb   + (size_t)r * DIM_C + q * 8;
  const ushort* apa = accb + (size_t)r * DIM_C + q * 8;

  f32x4 acc[8];
#pragma unroll
  for (int nt = 0; nt < 8; nt++) acc[nt] = (f32x4){0.f, 0.f, 0.f, 0.f};

#pragma unroll
  for (int ks = 0; ks < 4; ks++) {
    short8 af = *reinterpret_cast<const short8*>(aph + ks * 32);
#pragma unroll
    for (int nt = 0; nt < 8; nt++) {
      short8 bf = *reinterpret_cast<const short8*>(&Bl[nt * 16 + am][ks * 32 + q * 8]);
      acc[nt] = __builtin_amdgcn_mfma_f32_16x16x32_bf16(af, bf, acc[nt], 0, 0, 0);
    }
  }
#pragma unroll
  for (int ks = 0; ks < 4; ks++) {
    short8 af = *reinterpret_cast<const short8*>(apa + ks * 32);
#pragma unroll
    for (int nt = 0; nt < 8; nt++) {
      short8 bf = *reinterpret_cast<const short8*>(&Bl[nt * 16 + am][128 + ks * 32 + q * 8]);
      acc[nt] = __builtin_amdgcn_mfma_f32_16x16x32_bf16(af, bf, acc[nt], 0, 0, 0);
    }
  }

#pragma unroll
  for (int nt = 0; nt < 8; nt++) {
    int col = nt * 16 + am;
    float bv = bias_l[col];
#pragma unroll
    for (int rr = 0; rr < 4; rr++) {
      int row = m0 + q * 4 + rr;
      if (row < N_NODES_C) {
        float v = acc[nt][rr] + bv;
        out[(size_t)row * DIM_C + col] = fmaxf(v, 0.f);
      }
    }
  }
}

// --------------------------------------------------------------------------
extern "C" void kernel_launch(void* const* d_in, const int* in_sizes, int n_in,
                              void* d_out, int out_size, void* d_ws, size_t ws_size,
                              hipStream_t stream) {
  const float* h      = (const float*)d_in[0];
  const int*   src    = (const int*)d_in[1];
  const int*   dst    = (const int*)d_in[2];
  const float* deg    = (const float*)d_in[3];
  const float* Wself  = (const float*)d_in[4];
  const float* Wneigh = (const float*)d_in[5];
  const float* bias   = (const float*)d_in[6];
  float*       out    = (float*)d_out;

  char* ws = (char*)d_ws;
  ushort*   hb     = (ushort*)(ws + OFF_HB);
  ushort*   accb   = (ushort*)(ws + OFF_ACC);
  unsigned* packed = (unsigned*)(ws + OFF_PK);
  int*      esrc   = (int*)(ws + OFF_ESRC);
  int*      starts = (int*)(ws + OFF_ST);
  int*      ends   = (int*)(ws + OFF_EN);
  int*      gcur   = (int*)(ws + OFF_GC);
  ushort*   wb     = (ushort*)(ws + OFF_WB);

  // Zero the 196 bucket cursors only (784 B); all else fully overwritten.
  hipMemsetAsync(gcur, 0, NBKT * sizeof(int), stream);

  sage_cast_bucket<<<NB_CASTK + NB_WCAST + NB_SCAT, 1024, 0, stream>>>(
      h, hb, Wself, Wneigh, wb, src, dst, gcur, packed);
  sage_csr        <<<NBKT, 1024, 0, stream>>>(packed, gcur, starts, ends, esrc);
  sage_gather     <<<(N_NODES_C * 16) / 256, 256, 0, stream>>>(hb, starts, ends,
                                                               esrc, deg, accb);
  sage_gemm_mfma  <<<(N_NODES_C + 63) / 64, 256, 0, stream>>>(hb, accb, wb,
                                                              bias, out);
}

// Round 8
// 138.223 us; speedup vs baseline: 1.6563x; 1.0434x over previous
//
#include <hip/hip_runtime.h>

// GraphSAGE layer: out = relu(h @ Ws^T + (scatter_mean(h,src,dst)) @ Wn^T + b)
// N=50000, E=800000, dim 128.
// R8: (a) csr+gather fused per-bucket (sorted edge list stays in LDS; kills
//     esrc/starts/ends global round trip + one launch); (b) gemm 128
//     rows/block (halves W staging traffic, 2x MFMA per staged byte).
constexpr int N_NODES_C = 50000;
constexpr int N_EDGES_C = 800000;
constexpr int DIM_C     = 128;

constexpr int NBKT  = 196;    // (50000+255)>>8
constexpr int CAP   = 8192;   // bucket capacity; mean fill 4096, sd ~64
constexpr int NB_CASTK = 391; // h-cast blocks: 1024 thr x 16 elems, guarded
constexpr int NB_WCAST = 2;   // W-cast blocks: one per matrix
constexpr int NB_SCAT  = 196; // bucket-scatter blocks: 4096 edges each

typedef __attribute__((ext_vector_type(8))) short short8;  // 8 bf16, 4 VGPRs
typedef __attribute__((ext_vector_type(4))) float f32x4;

// Workspace layout (bytes), ~32.1 MB used:
constexpr size_t OFF_HB   = 0;                                   // ushort[N][128]
constexpr size_t OFF_ACC  = (size_t)N_NODES_C * DIM_C * 2;       // 12,800,000
constexpr size_t OFF_PK   = OFF_ACC + (size_t)N_NODES_C * DIM_C * 2;  // 25,600,000
constexpr size_t OFF_GC   = OFF_PK + (size_t)NBKT * CAP * 4;     // 32,022,528
constexpr size_t OFF_WB   = OFF_GC + 1024;                       // ushort[2][128][128]

// round-to-nearest-even f32 -> bf16 bits (finite inputs only)
static __device__ __forceinline__ ushort f2bf(float f) {
  unsigned u = __float_as_uint(f);
  return (ushort)((u + 0x7FFFu + ((u >> 16) & 1u)) >> 16);
}
static __device__ __forceinline__ unsigned pack2(float a, float b) {
  return (unsigned)f2bf(a) | ((unsigned)f2bf(b) << 16);
}

// --------------------------------------------------------------------------
// K_A: fused cast(h) + cast(W) + bucket scatter of packed edges.
// [0,NB_CASTK): h f32->bf16, 16 elems/thread.
// [NB_CASTK, +NB_WCAST): Wself/Wneigh f32->bf16 (16384 elems each).
// rest: 4096 edges -> LDS hist over 196 buckets -> one global atomicAdd per
//   nonzero bin (bulk reserve, ~38k total) -> scatter ((dst&255)<<16)|src.
// --------------------------------------------------------------------------
__global__ __launch_bounds__(1024) void sage_cast_bucket(
    const float* __restrict__ h, ushort* __restrict__ hb,
    const float* __restrict__ Wself, const float* __restrict__ Wneigh,
    ushort* __restrict__ wb,
    const int* __restrict__ src, const int* __restrict__ dst,
    int* __restrict__ gcur, unsigned* __restrict__ packed)
{
  const int b = blockIdx.x;
  const int t = threadIdx.x;
  if (b < NB_CASTK + NB_WCAST) {
    const float* sp;
    ushort* dp;
    size_t i;
    if (b < NB_CASTK) {
      int tid = b * 1024 + t;
      if (tid >= 400000) return;              // 400000*16 = 6.4M elems
      sp = h; dp = hb; i = (size_t)tid * 16;
    } else {
      int m = b - NB_CASTK;                   // 0: Wself, 1: Wneigh
      sp = m ? Wneigh : Wself;
      dp = wb + (size_t)m * DIM_C * DIM_C;
      i = (size_t)t * 16;                     // 1024*16 = 16384 exactly
    }
    float4 a0 = *reinterpret_cast<const float4*>(sp + i);
    float4 a1 = *reinterpret_cast<const float4*>(sp + i + 4);
    float4 a2 = *reinterpret_cast<const float4*>(sp + i + 8);
    float4 a3 = *reinterpret_cast<const float4*>(sp + i + 12);
    uint4 o0, o1;
    o0.x = pack2(a0.x, a0.y); o0.y = pack2(a0.z, a0.w);
    o0.z = pack2(a1.x, a1.y); o0.w = pack2(a1.z, a1.w);
    o1.x = pack2(a2.x, a2.y); o1.y = pack2(a2.z, a2.w);
    o1.z = pack2(a3.x, a3.y); o1.w = pack2(a3.z, a3.w);
    *reinterpret_cast<uint4*>(dp + i)     = o0;
    *reinterpret_cast<uint4*>(dp + i + 8) = o1;
    return;
  }

  __shared__ int bh[NBKT];     // per-bucket count
  __shared__ int bofs[NBKT];   // reserved base in bucket region
  __shared__ int bcur[NBKT];   // local cursor

  const int chunk = b - NB_CASTK - NB_WCAST;
  const int e = chunk * 4096 + t * 4;        // E%4==0: int4 valid when e<E

  if (t < NBKT) bh[t] = 0;
  __syncthreads();

  int4 d4, s4;
  bool live = (e < N_EDGES_C);
  if (live) {
    d4 = *reinterpret_cast<const int4*>(dst + e);
    s4 = *reinterpret_cast<const int4*>(src + e);
    atomicAdd(&bh[d4.x >> 8], 1);
    atomicAdd(&bh[d4.y >> 8], 1);
    atomicAdd(&bh[d4.z >> 8], 1);
    atomicAdd(&bh[d4.w >> 8], 1);
  }
  __syncthreads();

  if (t < NBKT) {
    bcur[t] = 0;
    bofs[t] = (bh[t] > 0) ? atomicAdd(&gcur[t], bh[t]) : 0;
  }
  __syncthreads();

  if (live) {
    int dd[4] = {d4.x, d4.y, d4.z, d4.w};
    int ss[4] = {s4.x, s4.y, s4.z, s4.w};
#pragma unroll
    for (int i = 0; i < 4; i++) {
      int bkt = dd[i] >> 8;
      int p = bofs[bkt] + atomicAdd(&bcur[bkt], 1);
      if (p < CAP)   // statistically unreachable; memory-safety guard
        packed[(size_t)bkt * CAP + p] =
            ((unsigned)(dd[i] & 255) << 16) | (unsigned)ss[i];
    }
  }
}

// --------------------------------------------------------------------------
// K_B: fused per-bucket counting sort + gather-mean. One 1024-thr block per
// bucket b (nodes [b*256,(b+1)*256)). Sorted edge list lives in LDS only:
//   phase 1: LDS hist over rid=dst&255;
//   phase 2: wave-0 shfl exclusive scan -> excl;
//   phase 3: placement into esrc_l (ushort, 16 KB), cursors in LDS;
//   phase 4: gather: 4 rounds x 64 nodes, 16 lanes/node x 8 bf16 (uint4),
//            esrc via LDS broadcast reads, f32 accum, fold 1/deg.
// --------------------------------------------------------------------------
__global__ __launch_bounds__(1024) void sage_csr_gather(
    const unsigned* __restrict__ packed, const int* __restrict__ gcur,
    const ushort* __restrict__ hb, const float* __restrict__ deg,
    ushort* __restrict__ accb)
{
  __shared__ int    hist[256];
  __shared__ int    excl[256];
  __shared__ int    curb[256];
  __shared__ ushort esrc_l[CAP];   // 16 KB

  const int b = blockIdx.x;
  const int t = threadIdx.x;
  const int count = min(gcur[b], CAP);
  const unsigned* pk = packed + (size_t)b * CAP;

  if (t < 256) hist[t] = 0;
  __syncthreads();

  for (int i = t; i < count; i += 1024)
    atomicAdd(&hist[pk[i] >> 16], 1);
  __syncthreads();

  // exclusive scan of hist[256] by wave 0: lane l owns bins 4l..4l+3
  if (t < 64) {
    int base = t * 4;
    int h0 = hist[base], h1 = hist[base + 1], h2 = hist[base + 2], h3 = hist[base + 3];
    int s = h0 + h1 + h2 + h3;
    int x = s;
#pragma unroll
    for (int d = 1; d < 64; d <<= 1) {
      int y = __shfl_up(x, d, 64);
      if (t >= d) x += y;
    }
    int ex = x - s;
    excl[base]     = ex;
    excl[base + 1] = ex + h0;
    excl[base + 2] = ex + h0 + h1;
    excl[base + 3] = ex + h0 + h1 + h2;
  }
  __syncthreads();

  if (t < 256) curb[t] = excl[t];
  __syncthreads();

  for (int i = t; i < count; i += 1024) {   // pk re-read is L2-hot
    unsigned w = pk[i];
    int p = atomicAdd(&curb[w >> 16], 1);
    esrc_l[p] = (ushort)(w & 0xFFFFu);
  }
  __syncthreads();

  // gather: 4 rounds of 64 nodes; 16 lanes per node, 8 bf16 per lane.
  const int c = (t & 15) << 3;
#pragma unroll
  for (int rd = 0; rd < 4; rd++) {
    int rid = rd * 64 + (t >> 4);
    int n = (b << 8) | rid;
    if (n >= N_NODES_C) continue;
    int begin = excl[rid];
    int end   = begin + hist[rid];

    float s0 = 0.f, s1 = 0.f, s2 = 0.f, s3 = 0.f;
    float s4 = 0.f, s5 = 0.f, s6 = 0.f, s7 = 0.f;

#define ACC8(u)                                                  \
    do {                                                         \
      s0 += __uint_as_float((u).x << 16);                        \
      s1 += __uint_as_float((u).x & 0xFFFF0000u);                \
      s2 += __uint_as_float((u).y << 16);                        \
      s3 += __uint_as_float((u).y & 0xFFFF0000u);                \
      s4 += __uint_as_float((u).z << 16);                        \
      s5 += __uint_as_float((u).z & 0xFFFF0000u);                \
      s6 += __uint_as_float((u).w << 16);                        \
      s7 += __uint_as_float((u).w & 0xFFFF0000u);                \
    } while (0)

    int i = begin;
    for (; i + 3 < end; i += 4) {
      int e0 = esrc_l[i], e1 = esrc_l[i + 1], e2 = esrc_l[i + 2], e3 = esrc_l[i + 3];
      uint4 a = *reinterpret_cast<const uint4*>(hb + (size_t)e0 * DIM_C + c);
      uint4 bb = *reinterpret_cast<const uint4*>(hb + (size_t)e1 * DIM_C + c);
      uint4 d = *reinterpret_cast<const uint4*>(hb + (size_t)e2 * DIM_C + c);
      uint4 f = *reinterpret_cast<const uint4*>(hb + (size_t)e3 * DIM_C + c);
      ACC8(a); ACC8(bb); ACC8(d); ACC8(f);
    }
    for (; i < end; i++) {
      int e0 = esrc_l[i];
      uint4 a = *reinterpret_cast<const uint4*>(hb + (size_t)e0 * DIM_C + c);
      ACC8(a);
    }
#undef ACC8

    float id = 1.0f / deg[n];
    uint4 o;
    o.x = pack2(s0 * id, s1 * id);
    o.y = pack2(s2 * id, s3 * id);
    o.z = pack2(s4 * id, s5 * id);
    o.w = pack2(s6 * id, s7 * id);
    *reinterpret_cast<uint4*>(accb + (size_t)n * DIM_C + c) = o;
  }
}

// --------------------------------------------------------------------------
// K4: fused bf16 MFMA GEMM, K=256 (k<128 from h_bf16, k>=128 from acc_bf16).
// Block = 256 thr (4 waves), 128 rows/block (2 row-tiles per wave: halves
// W-staging traffic per output row vs 64-row blocks). W staged from pre-cast
// bf16 global into padded LDS (uint4 copies).
// Layouts (m89/m91-verified): A[m=lane&15][k=quad*8+j];
// B from W[n][k] with n=lane&15, k=quad*8+j; C/D col=lane&15, row=quad*4+reg.
// --------------------------------------------------------------------------
__global__ __launch_bounds__(256) void sage_gemm_mfma(
    const ushort* __restrict__ hb, const ushort* __restrict__ accb,
    const ushort* __restrict__ wb, const float* __restrict__ bias,
    float* __restrict__ out)
{
  __shared__ ushort Bl[DIM_C][256 + 8];   // 67,584 B
  __shared__ float  bias_l[DIM_C];

  const int t = threadIdx.x;

  // Stage both W matrices: 128 rows x 16 uint4-chunks each, uint4 copies.
  for (int idx = t; idx < DIM_C * 16; idx += 256) {
    int n  = idx >> 4;
    int c8 = (idx & 15) << 3;
    uint4 w0 = *reinterpret_cast<const uint4*>(wb + (size_t)n * DIM_C + c8);
    uint4 w1 = *reinterpret_cast<const uint4*>(wb + (size_t)(DIM_C + n) * DIM_C + c8);
    *reinterpret_cast<uint4*>(&Bl[n][c8])       = w0;
    *reinterpret_cast<uint4*>(&Bl[n][128 + c8]) = w1;
  }
  if (t < DIM_C) bias_l[t] = bias[t];
  __syncthreads();

  const int lane = t & 63;
  const int w    = t >> 6;
  const int am   = lane & 15;
  const int q    = lane >> 4;
  const int mb   = blockIdx.x * 128;
  const int m0   = mb + w * 16;        // row-tile 0
  const int m1   = mb + 64 + w * 16;   // row-tile 1

  int r0 = m0 + am; if (r0 >= N_NODES_C) r0 = N_NODES_C - 1;
  int r1 = m1 + am; if (r1 >= N_NODES_C) r1 = N_NODES_C - 1;
  const ushort* aph0 = hb   + (size_t)r0 * DIM_C + q * 8;
  const ushort* apa0 = accb + (size_t)r0 * DIM_C + q * 8;
  const ushort* aph1 = hb   + (size_t)r1 * DIM_C + q * 8;
  const ushort* apa1 = accb + (size_t)r1 * DIM_C + q * 8;

  f32x4 acc[2][8];
#pragma unroll
  for (int i = 0; i < 2; i++)
#pragma unroll
    for (int nt = 0; nt < 8; nt++) acc[i][nt] = (f32x4){0.f, 0.f, 0.f, 0.f};

#pragma unroll
  for (int ks = 0; ks < 4; ks++) {
    short8 a0 = *reinterpret_cast<const short8*>(aph0 + ks * 32);
    short8 a1 = *reinterpret_cast<const short8*>(aph1 + ks * 32);
#pragma unroll
    for (int nt = 0; nt < 8; nt++) {
      short8 bf = *reinterpret_cast<const short8*>(&Bl[nt * 16 + am][ks * 32 + q * 8]);
      acc[0][nt] = __builtin_amdgcn_mfma_f32_16x16x32_bf16(a0, bf, acc[0][nt], 0, 0, 0);
      acc[1][nt] = __builtin_amdgcn_mfma_f32_16x16x32_bf16(a1, bf, acc[1][nt], 0, 0, 0);
    }
  }
#pragma unroll
  for (int ks = 0; ks < 4; ks++) {
    short8 a0 = *reinterpret_cast<const short8*>(apa0 + ks * 32);
    short8 a1 = *reinterpret_cast<const short8*>(apa1 + ks * 32);
#pragma unroll
    for (int nt = 0; nt < 8; nt++) {
      short8 bf = *reinterpret_cast<const short8*>(&Bl[nt * 16 + am][128 + ks * 32 + q * 8]);
      acc[0][nt] = __builtin_amdgcn_mfma_f32_16x16x32_bf16(a0, bf, acc[0][nt], 0, 0, 0);
      acc[1][nt] = __builtin_amdgcn_mfma_f32_16x16x32_bf16(a1, bf, acc[1][nt], 0, 0, 0);
    }
  }

#pragma unroll
  for (int i = 0; i < 2; i++) {
    int mt = (i == 0) ? m0 : m1;
#pragma unroll
    for (int nt = 0; nt < 8; nt++) {
      int col = nt * 16 + am;
      float bv = bias_l[col];
#pragma unroll
      for (int rr = 0; rr < 4; rr++) {
        int row = mt + q * 4 + rr;
        if (row < N_NODES_C) {
          float v = acc[i][nt][rr] + bv;
          out[(size_t)row * DIM_C + col] = fmaxf(v, 0.f);
        }
      }
    }
  }
}

// --------------------------------------------------------------------------
extern "C" void kernel_launch(void* const* d_in, const int* in_sizes, int n_in,
                              void* d_out, int out_size, void* d_ws, size_t ws_size,
                              hipStream_t stream) {
  const float* h      = (const float*)d_in[0];
  const int*   src    = (const int*)d_in[1];
  const int*   dst    = (const int*)d_in[2];
  const float* deg    = (const float*)d_in[3];
  const float* Wself  = (const float*)d_in[4];
  const float* Wneigh = (const float*)d_in[5];
  const float* bias   = (const float*)d_in[6];
  float*       out    = (float*)d_out;

  char* ws = (char*)d_ws;
  ushort*   hb     = (ushort*)(ws + OFF_HB);
  ushort*   accb   = (ushort*)(ws + OFF_ACC);
  unsigned* packed = (unsigned*)(ws + OFF_PK);
  int*      gcur   = (int*)(ws + OFF_GC);
  ushort*   wb     = (ushort*)(ws + OFF_WB);

  // Zero the 196 bucket cursors only (784 B); all else fully overwritten.
  hipMemsetAsync(gcur, 0, NBKT * sizeof(int), stream);

  sage_cast_bucket<<<NB_CASTK + NB_WCAST + NB_SCAT, 1024, 0, stream>>>(
      h, hb, Wself, Wneigh, wb, src, dst, gcur, packed);
  sage_csr_gather <<<NBKT, 1024, 0, stream>>>(packed, gcur, hb, deg, accb);
  sage_gemm_mfma  <<<(N_NODES_C + 127) / 128, 256, 0, stream>>>(hb, accb, wb,
                                                                bias, out);
}

// Round 9
// 137.548 us; speedup vs baseline: 1.6644x; 1.0049x over previous
//
#include <hip/hip_runtime.h>

// GraphSAGE layer: out = relu(h @ Ws^T + (scatter_mean(h,src,dst)) @ Wn^T + b)
// N=50000, E=800000, dim 128.
// R9: (a) csr_gather split 4 sub-blocks/bucket (784x256 vs 196x1024: R8 left
//     60 CUs idle in the heaviest kernel); 1/deg now derived from LDS hist;
//     (b) cast_bucket dispatches scatter blocks first so cast blocks overlap
//     into their shadow.
constexpr int N_NODES_C = 50000;
constexpr int N_EDGES_C = 800000;
constexpr int DIM_C     = 128;

constexpr int NBKT  = 196;    // (50000+255)>>8
constexpr int CAP   = 8192;   // bucket capacity; mean fill 4096, sd ~64
constexpr int NB_SCAT  = 196; // bucket-scatter blocks: 4096 edges each
constexpr int NB_WCAST = 2;   // W-cast blocks: one per matrix
constexpr int NB_CASTK = 391; // h-cast blocks: 1024 thr x 16 elems, guarded

constexpr int SUBS    = 4;    // csr_gather sub-blocks per bucket
constexpr int NSUB    = 64;   // nodes per sub-block
constexpr int CAP_SUB = 2048; // sub-block edge capacity; mean 1024, sd ~32

typedef __attribute__((ext_vector_type(8))) short short8;  // 8 bf16, 4 VGPRs
typedef __attribute__((ext_vector_type(4))) float f32x4;

// Workspace layout (bytes), ~32.1 MB used:
constexpr size_t OFF_HB   = 0;                                   // ushort[N][128]
constexpr size_t OFF_ACC  = (size_t)N_NODES_C * DIM_C * 2;       // 12,800,000
constexpr size_t OFF_PK   = OFF_ACC + (size_t)N_NODES_C * DIM_C * 2;  // 25,600,000
constexpr size_t OFF_GC   = OFF_PK + (size_t)NBKT * CAP * 4;     // 32,022,528
constexpr size_t OFF_WB   = OFF_GC + 1024;                       // ushort[2][128][128]

// round-to-nearest-even f32 -> bf16 bits (finite inputs only)
static __device__ __forceinline__ ushort f2bf(float f) {
  unsigned u = __float_as_uint(f);
  return (ushort)((u + 0x7FFFu + ((u >> 16) & 1u)) >> 16);
}
static __device__ __forceinline__ unsigned pack2(float a, float b) {
  return (unsigned)f2bf(a) | ((unsigned)f2bf(b) << 16);
}

// --------------------------------------------------------------------------
// K_A: fused bucket scatter + cast(W) + cast(h), in that dispatch order so
// the heavyweight scatter blocks start immediately.
// scatter: 4096 edges -> LDS hist over 196 buckets -> one global atomicAdd
//   per nonzero bin (bulk reserve, ~38k total) -> scatter ((dst&255)<<16)|src.
// --------------------------------------------------------------------------
__global__ __launch_bounds__(1024) void sage_cast_bucket(
    const float* __restrict__ h, ushort* __restrict__ hb,
    const float* __restrict__ Wself, const float* __restrict__ Wneigh,
    ushort* __restrict__ wb,
    const int* __restrict__ src, const int* __restrict__ dst,
    int* __restrict__ gcur, unsigned* __restrict__ packed)
{
  const int b = blockIdx.x;
  const int t = threadIdx.x;
  if (b >= NB_SCAT) {
    const float* sp;
    ushort* dp;
    size_t i;
    if (b < NB_SCAT + NB_WCAST) {
      int m = b - NB_SCAT;                    // 0: Wself, 1: Wneigh
      sp = m ? Wneigh : Wself;
      dp = wb + (size_t)m * DIM_C * DIM_C;
      i = (size_t)t * 16;                     // 1024*16 = 16384 exactly
    } else {
      int tid = (b - NB_SCAT - NB_WCAST) * 1024 + t;
      if (tid >= 400000) return;              // 400000*16 = 6.4M elems
      sp = h; dp = hb; i = (size_t)tid * 16;
    }
    float4 a0 = *reinterpret_cast<const float4*>(sp + i);
    float4 a1 = *reinterpret_cast<const float4*>(sp + i + 4);
    float4 a2 = *reinterpret_cast<const float4*>(sp + i + 8);
    float4 a3 = *reinterpret_cast<const float4*>(sp + i + 12);
    uint4 o0, o1;
    o0.x = pack2(a0.x, a0.y); o0.y = pack2(a0.z, a0.w);
    o0.z = pack2(a1.x, a1.y); o0.w = pack2(a1.z, a1.w);
    o1.x = pack2(a2.x, a2.y); o1.y = pack2(a2.z, a2.w);
    o1.z = pack2(a3.x, a3.y); o1.w = pack2(a3.z, a3.w);
    *reinterpret_cast<uint4*>(dp + i)     = o0;
    *reinterpret_cast<uint4*>(dp + i + 8) = o1;
    return;
  }

  __shared__ int bh[NBKT];     // per-bucket count
  __shared__ int bofs[NBKT];   // reserved base in bucket region
  __shared__ int bcur[NBKT];   // local cursor

  const int e = b * 4096 + t * 4;            // E%4==0: int4 valid when e<E

  if (t < NBKT) bh[t] = 0;
  __syncthreads();

  int4 d4, s4;
  bool live = (e < N_EDGES_C);
  if (live) {
    d4 = *reinterpret_cast<const int4*>(dst + e);
    s4 = *reinterpret_cast<const int4*>(src + e);
    atomicAdd(&bh[d4.x >> 8], 1);
    atomicAdd(&bh[d4.y >> 8], 1);
    atomicAdd(&bh[d4.z >> 8], 1);
    atomicAdd(&bh[d4.w >> 8], 1);
  }
  __syncthreads();

  if (t < NBKT) {
    bcur[t] = 0;
    bofs[t] = (bh[t] > 0) ? atomicAdd(&gcur[t], bh[t]) : 0;
  }
  __syncthreads();

  if (live) {
    int dd[4] = {d4.x, d4.y, d4.z, d4.w};
    int ss[4] = {s4.x, s4.y, s4.z, s4.w};
#pragma unroll
    for (int i = 0; i < 4; i++) {
      int bkt = dd[i] >> 8;
      int p = bofs[bkt] + atomicAdd(&bcur[bkt], 1);
      if (p < CAP)   // statistically unreachable; memory-safety guard
        packed[(size_t)bkt * CAP + p] =
            ((unsigned)(dd[i] & 255) << 16) | (unsigned)ss[i];
    }
  }
}

// --------------------------------------------------------------------------
// K_B: per-sub-bucket counting sort + gather-mean. Block (bucket b, sub s)
// owns node-ids rid in [s*64, s*64+64) of bucket b. 784 blocks x 256 thr
// (~5 KB LDS -> ~8 blocks/CU resident; dynamic dispatch load-balances all
// 256 CUs, unlike R8's 196x1024).
//   pass 1: uint4-vectorized filtered scan of the bucket run -> hist[64];
//   scan:   wave-0 shfl exclusive scan (1 bin/lane);
//   pass 2: filtered placement into esrc_l (LDS cursors);
//   gather: 4 rounds x 16 nodes, 16 lanes/node x 8 bf16 (uint4);
//           1/deg = 1/max(hist,1) (== input deg by construction).
// --------------------------------------------------------------------------
__global__ __launch_bounds__(256) void sage_csr_gather(
    const unsigned* __restrict__ packed, const int* __restrict__ gcur,
    const ushort* __restrict__ hb, ushort* __restrict__ accb)
{
  __shared__ int    hist[NSUB];
  __shared__ int    excl_s[NSUB];
  __shared__ int    curb[NSUB];
  __shared__ ushort esrc_l[CAP_SUB];   // 4 KB

  const int b   = blockIdx.x >> 2;     // bucket
  const int sub = blockIdx.x & 3;
  const int rlo = sub * NSUB;
  const int t = threadIdx.x;
  const int count = min(gcur[b], CAP);
  const unsigned* pk = packed + (size_t)b * CAP;
  const int nvec = count >> 2;
  const int ntail = count & 3;

  if (t < NSUB) hist[t] = 0;
  __syncthreads();

  // pass 1: histogram of our rid range (vectorized scan, L2-hot)
  for (int g = t; g < nvec; g += 256) {
    uint4 w4 = *reinterpret_cast<const uint4*>(pk + g * 4);
    int r;
    r = (int)(w4.x >> 16) - rlo; if ((unsigned)r < (unsigned)NSUB) atomicAdd(&hist[r], 1);
    r = (int)(w4.y >> 16) - rlo; if ((unsigned)r < (unsigned)NSUB) atomicAdd(&hist[r], 1);
    r = (int)(w4.z >> 16) - rlo; if ((unsigned)r < (unsigned)NSUB) atomicAdd(&hist[r], 1);
    r = (int)(w4.w >> 16) - rlo; if ((unsigned)r < (unsigned)NSUB) atomicAdd(&hist[r], 1);
  }
  if (t < ntail) {
    int r = (int)(pk[nvec * 4 + t] >> 16) - rlo;
    if ((unsigned)r < (unsigned)NSUB) atomicAdd(&hist[r], 1);
  }
  __syncthreads();

  // exclusive scan of hist[64] by wave 0 (1 bin per lane)
  if (t < 64) {
    int v = hist[t];
    int x = v;
#pragma unroll
    for (int d = 1; d < 64; d <<= 1) {
      int y = __shfl_up(x, d, 64);
      if (t >= d) x += y;
    }
    excl_s[t] = x - v;
    curb[t]   = x - v;
  }
  __syncthreads();

  // pass 2: filtered placement
  for (int g = t; g < nvec; g += 256) {
    uint4 w4 = *reinterpret_cast<const uint4*>(pk + g * 4);
    unsigned ww[4] = {w4.x, w4.y, w4.z, w4.w};
#pragma unroll
    for (int j = 0; j < 4; j++) {
      int r = (int)(ww[j] >> 16) - rlo;
      if ((unsigned)r < (unsigned)NSUB) {
        int p = atomicAdd(&curb[r], 1);
        esrc_l[p] = (ushort)(ww[j] & 0xFFFFu);
      }
    }
  }
  if (t < ntail) {
    unsigned w = pk[nvec * 4 + t];
    int r = (int)(w >> 16) - rlo;
    if ((unsigned)r < (unsigned)NSUB) {
      int p = atomicAdd(&curb[r], 1);
      esrc_l[p] = (ushort)(w & 0xFFFFu);
    }
  }
  __syncthreads();

  // gather: 4 rounds x 16 nodes; 16 lanes per node, 8 bf16 per lane.
  const int c = (t & 15) << 3;
#pragma unroll
  for (int rd = 0; rd < 4; rd++) {
    int lr = rd * 16 + (t >> 4);     // local rid 0..63
    int n = (b << 8) + rlo + lr;
    if (n >= N_NODES_C) continue;
    int begin = excl_s[lr];
    int cnt   = hist[lr];
    int end   = begin + cnt;

    float s0 = 0.f, s1 = 0.f, s2 = 0.f, s3 = 0.f;
    float s4 = 0.f, s5 = 0.f, s6 = 0.f, s7 = 0.f;

#define ACC8(u)                                                  \
    do {                                                         \
      s0 += __uint_as_float((u).x << 16);                        \
      s1 += __uint_as_float((u).x & 0xFFFF0000u);                \
      s2 += __uint_as_float((u).y << 16);                        \
      s3 += __uint_as_float((u).y & 0xFFFF0000u);                \
      s4 += __uint_as_float((u).z << 16);                        \
      s5 += __uint_as_float((u).z & 0xFFFF0000u);                \
      s6 += __uint_as_float((u).w << 16);                        \
      s7 += __uint_as_float((u).w & 0xFFFF0000u);                \
    } while (0)

    int i = begin;
    for (; i + 3 < end; i += 4) {
      int e0 = esrc_l[i], e1 = esrc_l[i + 1], e2 = esrc_l[i + 2], e3 = esrc_l[i + 3];
      uint4 a  = *reinterpret_cast<const uint4*>(hb + (size_t)e0 * DIM_C + c);
      uint4 bb = *reinterpret_cast<const uint4*>(hb + (size_t)e1 * DIM_C + c);
      uint4 d  = *reinterpret_cast<const uint4*>(hb + (size_t)e2 * DIM_C + c);
      uint4 f  = *reinterpret_cast<const uint4*>(hb + (size_t)e3 * DIM_C + c);
      ACC8(a); ACC8(bb); ACC8(d); ACC8(f);
    }
    for (; i < end; i++) {
      int e0 = esrc_l[i];
      uint4 a = *reinterpret_cast<const uint4*>(hb + (size_t)e0 * DIM_C + c);
      ACC8(a);
    }
#undef ACC8

    float id = 1.0f / (float)max(cnt, 1);   // == 1/deg[n] by construction
    uint4 o;
    o.x = pack2(s0 * id, s1 * id);
    o.y = pack2(s2 * id, s3 * id);
    o.z = pack2(s4 * id, s5 * id);
    o.w = pack2(s6 * id, s7 * id);
    *reinterpret_cast<uint4*>(accb + (size_t)n * DIM_C + c) = o;
  }
}

// --------------------------------------------------------------------------
// K4: fused bf16 MFMA GEMM, K=256 (k<128 from h_bf16, k>=128 from acc_bf16).
// Block = 256 thr (4 waves), 128 rows/block. W staged from pre-cast bf16
// global into padded LDS (uint4 copies).
// Layouts (m89/m91-verified): A[m=lane&15][k=quad*8+j];
// B from W[n][k] with n=lane&15, k=quad*8+j; C/D col=lane&15, row=quad*4+reg.
// --------------------------------------------------------------------------
__global__ __launch_bounds__(256) void sage_gemm_mfma(
    const ushort* __restrict__ hb, const ushort* __restrict__ accb,
    const ushort* __restrict__ wb, const float* __restrict__ bias,
    float* __restrict__ out)
{
  __shared__ ushort Bl[DIM_C][256 + 8];   // 67,584 B
  __shared__ float  bias_l[DIM_C];

  const int t = threadIdx.x;

  for (int idx = t; idx < DIM_C * 16; idx += 256) {
    int n  = idx >> 4;
    int c8 = (idx & 15) << 3;
    uint4 w0 = *reinterpret_cast<const uint4*>(wb + (size_t)n * DIM_C + c8);
    uint4 w1 = *reinterpret_cast<const uint4*>(wb + (size_t)(DIM_C + n) * DIM_C + c8);
    *reinterpret_cast<uint4*>(&Bl[n][c8])       = w0;
    *reinterpret_cast<uint4*>(&Bl[n][128 + c8]) = w1;
  }
  if (t < DIM_C) bias_l[t] = bias[t];
  __syncthreads();

  const int lane = t & 63;
  const int w    = t >> 6;
  const int am   = lane & 15;
  const int q    = lane >> 4;
  const int mb   = blockIdx.x * 128;
  const int m0   = mb + w * 16;        // row-tile 0
  const int m1   = mb + 64 + w * 16;   // row-tile 1

  int r0 = m0 + am; if (r0 >= N_NODES_C) r0 = N_NODES_C - 1;
  int r1 = m1 + am; if (r1 >= N_NODES_C) r1 = N_NODES_C - 1;
  const ushort* aph0 = hb   + (size_t)r0 * DIM_C + q * 8;
  const ushort* apa0 = accb + (size_t)r0 * DIM_C + q * 8;
  const ushort* aph1 = hb   + (size_t)r1 * DIM_C + q * 8;
  const ushort* apa1 = accb + (size_t)r1 * DIM_C + q * 8;

  f32x4 acc[2][8];
#pragma unroll
  for (int i = 0; i < 2; i++)
#pragma unroll
    for (int nt = 0; nt < 8; nt++) acc[i][nt] = (f32x4){0.f, 0.f, 0.f, 0.f};

#pragma unroll
  for (int ks = 0; ks < 4; ks++) {
    short8 a0 = *reinterpret_cast<const short8*>(aph0 + ks * 32);
    short8 a1 = *reinterpret_cast<const short8*>(aph1 + ks * 32);
#pragma unroll
    for (int nt = 0; nt < 8; nt++) {
      short8 bf = *reinterpret_cast<const short8*>(&Bl[nt * 16 + am][ks * 32 + q * 8]);
      acc[0][nt] = __builtin_amdgcn_mfma_f32_16x16x32_bf16(a0, bf, acc[0][nt], 0, 0, 0);
      acc[1][nt] = __builtin_amdgcn_mfma_f32_16x16x32_bf16(a1, bf, acc[1][nt], 0, 0, 0);
    }
  }
#pragma unroll
  for (int ks = 0; ks < 4; ks++) {
    short8 a0 = *reinterpret_cast<const short8*>(apa0 + ks * 32);
    short8 a1 = *reinterpret_cast<const short8*>(apa1 + ks * 32);
#pragma unroll
    for (int nt = 0; nt < 8; nt++) {
      short8 bf = *reinterpret_cast<const short8*>(&Bl[nt * 16 + am][128 + ks * 32 + q * 8]);
      acc[0][nt] = __builtin_amdgcn_mfma_f32_16x16x32_bf16(a0, bf, acc[0][nt], 0, 0, 0);
      acc[1][nt] = __builtin_amdgcn_mfma_f32_16x16x32_bf16(a1, bf, acc[1][nt], 0, 0, 0);
    }
  }

#pragma unroll
  for (int i = 0; i < 2; i++) {
    int mt = (i == 0) ? m0 : m1;
#pragma unroll
    for (int nt = 0; nt < 8; nt++) {
      int col = nt * 16 + am;
      float bv = bias_l[col];
#pragma unroll
      for (int rr = 0; rr < 4; rr++) {
        int row = mt + q * 4 + rr;
        if (row < N_NODES_C) {
          float v = acc[i][nt][rr] + bv;
          out[(size_t)row * DIM_C + col] = fmaxf(v, 0.f);
        }
      }
    }
  }
}

// --------------------------------------------------------------------------
extern "C" void kernel_launch(void* const* d_in, const int* in_sizes, int n_in,
                              void* d_out, int out_size, void* d_ws, size_t ws_size,
                              hipStream_t stream) {
  const float* h      = (const float*)d_in[0];
  const int*   src    = (const int*)d_in[1];
  const int*   dst    = (const int*)d_in[2];
  const float* Wself  = (const float*)d_in[4];
  const float* Wneigh = (const float*)d_in[5];
  const float* bias   = (const float*)d_in[6];
  float*       out    = (float*)d_out;

  char* ws = (char*)d_ws;
  ushort*   hb     = (ushort*)(ws + OFF_HB);
  ushort*   accb   = (ushort*)(ws + OFF_ACC);
  unsigned* packed = (unsigned*)(ws + OFF_PK);
  int*      gcur   = (int*)(ws + OFF_GC);
  ushort*   wb     = (ushort*)(ws + OFF_WB);

  // Zero the 196 bucket cursors only (784 B); all else fully overwritten.
  hipMemsetAsync(gcur, 0, NBKT * sizeof(int), stream);

  sage_cast_bucket<<<NB_SCAT + NB_WCAST + NB_CASTK, 1024, 0, stream>>>(
      h, hb, Wself, Wneigh, wb, src, dst, gcur, packed);
  sage_csr_gather <<<NBKT * SUBS, 256, 0, stream>>>(packed, gcur, hb, accb);
  sage_gemm_mfma  <<<(N_NODES_C + 127) / 128, 256, 0, stream>>>(hb, accb, wb,
                                                                bias, out);
}